// Round 7
// baseline (269.366 us; speedup 1.0000x reference)
//
#include <hip/hip_runtime.h>
#include <hip/hip_bf16.h>
#include <math.h>

#define Bn 8
#define Sn 1024
#define Dn 512
#define Hn 8
#define HDn 64

typedef __bf16 bf16x8 __attribute__((ext_vector_type(8)));
typedef __bf16 bf16x4 __attribute__((ext_vector_type(4)));
typedef float  f32x4  __attribute__((ext_vector_type(4)));

// ---------------- Kernel 1: h = emb[x] + positional embedding ----------------
__global__ void k_embed(const int* __restrict__ x, const float* __restrict__ emb,
                        float* __restrict__ h) {
    const int total = Bn * Sn * Dn;
    for (int i = blockIdx.x * blockDim.x + threadIdx.x; i < total; i += gridDim.x * blockDim.x) {
        int d = i & (Dn - 1);
        int bs = i >> 9;           // b*S + s
        int s = bs & (Sn - 1);
        int tok = x[bs];
        float f = __expf((float)(d & ~1) * (-9.210340371976184f / 512.0f));
        float ang = (float)s * f;
        float pe = (d & 1) ? __cosf(ang) : __sinf(ang);
        h[i] = emb[(size_t)tok * Dn + d] + pe;
    }
}

// ---------------- Kernel 2: width[b,s] = h . Wc + bc (one wave per row) ------
__global__ void k_width(const float* __restrict__ h, const float* __restrict__ Wc,
                        const float* __restrict__ bc, float* __restrict__ width) {
    int row = blockIdx.x * 4 + (threadIdx.x >> 6);
    int lane = threadIdx.x & 63;
    const float* hr = h + (size_t)row * Dn;
    float acc = 0.f;
    for (int i = lane; i < Dn; i += 64) acc += hr[i] * Wc[i];
    for (int off = 32; off > 0; off >>= 1) acc += __shfl_down(acc, off);
    if (lane == 0) width[row] = acc + bc[0];
}

// ---------------- Kernel 3: per-batch min/max over S -------------------------
__global__ void k_minmax(const float* __restrict__ width, float* __restrict__ lo,
                         float* __restrict__ hi) {
    int b = blockIdx.x;
    __shared__ float smin[256], smax[256];
    float mn = 1e30f, mx = -1e30f;
    for (int s = threadIdx.x; s < Sn; s += 256) {
        float v = width[b * Sn + s];
        mn = fminf(mn, v);
        mx = fmaxf(mx, v);
    }
    smin[threadIdx.x] = mn; smax[threadIdx.x] = mx;
    __syncthreads();
    for (int off = 128; off; off >>= 1) {
        if (threadIdx.x < off) {
            smin[threadIdx.x] = fminf(smin[threadIdx.x], smin[threadIdx.x + off]);
            smax[threadIdx.x] = fmaxf(smax[threadIdx.x], smax[threadIdx.x + off]);
        }
        __syncthreads();
    }
    if (threadIdx.x == 0) { lo[b] = smin[0]; hi[b] = smax[0]; }
}

// ---------------- Kernel 4: mask -> f32 d_out tail (+ wn for k_attn) ---------
__global__ void k_mask(const float* __restrict__ width, const float* __restrict__ lo,
                       const float* __restrict__ hi, float* __restrict__ mask_out,
                       float* __restrict__ wn_out) {
    int bs = blockIdx.x;           // b*S + s
    int b = bs >> 10;
    int s = bs & (Sn - 1);
    float wn = (width[bs] - lo[b]) / (hi[b] - lo[b]);
    if (threadIdx.x == 0) wn_out[bs] = wn;
    for (int t = threadIdx.x; t < Sn; t += 256) {
        int it = (t - s + 1535) & (Sn - 1);
        float origin = (it < 512) ? (1.0f - (float)it * (1.0f / 511.0f))
                                  : ((float)(it - 512) * (1.0f / 511.0f));
        float z = (origin - wn) * 100.0f;
        float om;
        if (z >= 0.0f) { float e = __expf(-z); om = e / (1.0f + e); }
        else           { float e = __expf(z);  om = 1.0f / (1.0f + e); }
        bool cmpv = (it >= t);
        bool mv = (s < 512) ? cmpv : !cmpv;
        mask_out[(size_t)bs * Sn + t] = mv ? om : 0.0f;
    }
}

// ---------------- Kernel 5: MFMA q,k,v -------------------------------------
// h viewed as [65536 x 64] rows (row R = bs*8 + head; Wq/Wk/Wv shared across
// heads). One 64-row tile per block; weights staged row-major in LDS (B-frag
// = contiguous bf16x8 from row n*16+li, same pattern as k_proj).
// q,k: [B,H,S,HD] bf16 ; vt: [B,H,HD,S] bf16 via LDS transpose.
__global__ __launch_bounds__(256) void k_qkv(
        const float* __restrict__ h, const float* __restrict__ Wq,
        const float* __restrict__ Wk, const float* __restrict__ Wv,
        __bf16* __restrict__ q, __bf16* __restrict__ k, __bf16* __restrict__ vt) {
    __shared__ __align__(16) __bf16 Xs[64][72];
    __shared__ __align__(16) __bf16 WqS[64][72];   // [o][d], rows as-is
    __shared__ __align__(16) __bf16 WkS[64][72];
    __shared__ __align__(16) __bf16 WvS[64][72];
    int t = threadIdx.x;
    int m0 = blockIdx.x * 64;          // global row base (R = bs*8 + head)
    int w = t >> 6, lane = t & 63, quad = lane >> 4, li = lane & 15;

    #pragma unroll
    for (int it = 0; it < 4; ++it) {
        int e = (it * 256 + t) * 4; int r = e >> 6, c = e & 63;
        float4 xv = *(const float4*)&h[(size_t)(m0 + r) * 64 + c];
        *(bf16x4*)&Xs[r][c]  = (bf16x4){(__bf16)xv.x, (__bf16)xv.y, (__bf16)xv.z, (__bf16)xv.w};
        float4 qv = *(const float4*)&Wq[e];
        *(bf16x4*)&WqS[r][c] = (bf16x4){(__bf16)qv.x, (__bf16)qv.y, (__bf16)qv.z, (__bf16)qv.w};
        float4 kv = *(const float4*)&Wk[e];
        *(bf16x4*)&WkS[r][c] = (bf16x4){(__bf16)kv.x, (__bf16)kv.y, (__bf16)kv.z, (__bf16)kv.w};
        float4 vv = *(const float4*)&Wv[e];
        *(bf16x4*)&WvS[r][c] = (bf16x4){(__bf16)vv.x, (__bf16)vv.y, (__bf16)vv.z, (__bf16)vv.w};
    }
    __syncthreads();

    bf16x8 A0 = *(const bf16x8*)&Xs[w * 16 + li][quad * 8];
    bf16x8 A1 = *(const bf16x8*)&Xs[w * 16 + li][32 + quad * 8];
    f32x4 aq[4], ak[4], av[4];
    #pragma unroll
    for (int n = 0; n < 4; ++n) {
        aq[n] = (f32x4){0.f,0.f,0.f,0.f}; ak[n] = aq[n]; av[n] = aq[n];
        bf16x8 Bq0 = *(const bf16x8*)&WqS[n * 16 + li][quad * 8];
        bf16x8 Bq1 = *(const bf16x8*)&WqS[n * 16 + li][32 + quad * 8];
        aq[n] = __builtin_amdgcn_mfma_f32_16x16x32_bf16(A0, Bq0, aq[n], 0, 0, 0);
        aq[n] = __builtin_amdgcn_mfma_f32_16x16x32_bf16(A1, Bq1, aq[n], 0, 0, 0);
        bf16x8 Bk0 = *(const bf16x8*)&WkS[n * 16 + li][quad * 8];
        bf16x8 Bk1 = *(const bf16x8*)&WkS[n * 16 + li][32 + quad * 8];
        ak[n] = __builtin_amdgcn_mfma_f32_16x16x32_bf16(A0, Bk0, ak[n], 0, 0, 0);
        ak[n] = __builtin_amdgcn_mfma_f32_16x16x32_bf16(A1, Bk1, ak[n], 0, 0, 0);
        bf16x8 Bv0 = *(const bf16x8*)&WvS[n * 16 + li][quad * 8];
        bf16x8 Bv1 = *(const bf16x8*)&WvS[n * 16 + li][32 + quad * 8];
        av[n] = __builtin_amdgcn_mfma_f32_16x16x32_bf16(A0, Bv0, av[n], 0, 0, 0);
        av[n] = __builtin_amdgcn_mfma_f32_16x16x32_bf16(A1, Bv1, av[n], 0, 0, 0);
    }

    // q,k stores (C layout: row=quad*4+r local, col=n*16+li)
    #pragma unroll
    for (int n = 0; n < 4; ++n)
        #pragma unroll
        for (int r = 0; r < 4; ++r) {
            int Rg = m0 + w * 16 + quad * 4 + r;
            int bsI = Rg >> 3, head = Rg & 7;
            int b = bsI >> 10, s = bsI & (Sn - 1);
            size_t oidx = (((size_t)(b * Hn + head)) * Sn + s) * HDn + n * 16 + li;
            q[oidx] = (__bf16)aq[n][r];
            k[oidx] = (__bf16)ak[n][r];
        }

    // v: LDS transpose (reuse WqS) then coalesced vt write
    __bf16 (*Vs)[72] = WqS;
    __syncthreads();               // all fragment reads done
    #pragma unroll
    for (int n = 0; n < 4; ++n)
        #pragma unroll
        for (int r = 0; r < 4; ++r)
            Vs[w * 16 + quad * 4 + r][n * 16 + li] = (__bf16)av[n][r];
    __syncthreads();
    int bs0 = m0 >> 3;
    int b = bs0 >> 10, s0l = bs0 & (Sn - 1);
    #pragma unroll
    for (int i = 0; i < 2; ++i) {
        int p = t + 256 * i;       // (head, o) pair
        int head = p >> 6, o = p & 63;
        __bf16 tmp[8];
        #pragma unroll
        for (int j = 0; j < 8; ++j) tmp[j] = Vs[j * 8 + head][o];
        *(bf16x8*)&vt[(((size_t)(b * Hn + head)) * HDn + o) * Sn + s0l] = *(bf16x8*)tmp;
    }
}

// ---------------- Kernel 6: MFMA flash attention, inline mask ----------------
// grid: (b*H+h)*16 + qtile ; 256 thr = 4 waves; wave w owns q-rows [w*16,+16)
__global__ __launch_bounds__(256) void k_attn(
        const __bf16* __restrict__ q, const __bf16* __restrict__ k,
        const __bf16* __restrict__ vt, const float* __restrict__ wn,
        __bf16* __restrict__ ao) {
    const float SCALE = 0.04419417382415922f;  // 1/sqrt(512)
    __shared__ __align__(16) __bf16 Qs[64][72];
    __shared__ __align__(16) __bf16 Ks[64][72];
    __shared__ __align__(16) __bf16 Vt[64][72];   // [o][k_local]
    __shared__ __align__(16) __bf16 Ps[64][72];
    int blk = blockIdx.x;
    int qt = blk & 15;
    int bh = blk >> 4;
    int hh = bh & (Hn - 1);
    int b = bh >> 3;
    int q0 = qt * 64;
    int t = threadIdx.x;
    int w = t >> 6, lane = t & 63, quad = lane >> 4, li = lane & 15;

    const __bf16* qbase  = q  + ((size_t)bh * Sn + q0) * HDn;
    const __bf16* kbase  = k  + (size_t)bh * Sn * HDn;
    const __bf16* vtbase = vt + (size_t)bh * HDn * Sn;

    #pragma unroll
    for (int it = 0; it < 2; ++it) {
        int e = (it * 256 + t) * 8; int r = e >> 6, c = e & 63;
        *(bf16x8*)&Qs[r][c] = *(const bf16x8*)&qbase[e];
    }

    // per-row mask constants (B==H quirk: batch index = hh)
    int qrow[4]; float wn100[4]; bool qlt[4];
    #pragma unroll
    for (int r = 0; r < 4; ++r) {
        qrow[r] = q0 + w * 16 + quad * 4 + r;
        wn100[r] = wn[hh * Sn + qrow[r]] * 100.0f;
        qlt[r] = qrow[r] < 512;
    }
    __syncthreads();
    bf16x8 A0 = *(const bf16x8*)&Qs[w * 16 + li][quad * 8];       // loop-invariant
    bf16x8 A1 = *(const bf16x8*)&Qs[w * 16 + li][32 + quad * 8];

    f32x4 O[4];
    #pragma unroll
    for (int n = 0; n < 4; ++n) O[n] = (f32x4){0.f, 0.f, 0.f, 0.f};
    float m_[4] = {-1e30f, -1e30f, -1e30f, -1e30f};
    float l_[4] = {0.f, 0.f, 0.f, 0.f};

    for (int k0 = 0; k0 < Sn; k0 += 64) {
        if (k0) __syncthreads();
        #pragma unroll
        for (int it = 0; it < 2; ++it) {
            int e = (it * 256 + t) * 8; int r = e >> 6, c = e & 63;
            *(bf16x8*)&Ks[r][c] = *(const bf16x8*)&kbase[(size_t)k0 * HDn + e];
            *(bf16x8*)&Vt[r][c] = *(const bf16x8*)&vtbase[(size_t)r * Sn + k0 + c];
        }
        __syncthreads();

        // ---- S = Q K^T ----
        f32x4 Sf[4];
        #pragma unroll
        for (int n = 0; n < 4; ++n) {
            f32x4 acc = (f32x4){0.f, 0.f, 0.f, 0.f};
            bf16x8 B0 = *(const bf16x8*)&Ks[n * 16 + li][quad * 8];
            acc = __builtin_amdgcn_mfma_f32_16x16x32_bf16(A0, B0, acc, 0, 0, 0);
            bf16x8 B1 = *(const bf16x8*)&Ks[n * 16 + li][32 + quad * 8];
            acc = __builtin_amdgcn_mfma_f32_16x16x32_bf16(A1, B1, acc, 0, 0, 0);
            Sf[n] = acc;
        }

        // ---- inline converable mask * scale ----
        #pragma unroll
        for (int n = 0; n < 4; ++n) {
            int col = k0 + n * 16 + li;
            #pragma unroll
            for (int r = 0; r < 4; ++r) {
                int it2 = (col - qrow[r] + 1535) & (Sn - 1);
                float origin = (it2 < 512) ? fmaf((float)it2, -1.0f / 511.0f, 1.0f)
                                           : (float)(it2 - 512) * (1.0f / 511.0f);
                float z = fmaf(origin, 100.0f, -wn100[r]);
                float om = __fdividef(1.0f, 1.0f + __expf(z));   // z=+inf -> 0, -inf -> 1
                bool mv = qlt[r] ? (it2 >= col) : (it2 < col);
                Sf[n][r] *= (mv ? om : 0.0f) * SCALE;
            }
        }

        // ---- online softmax (rows in quads; reduce over 16 lanes) ----
        float mx[4];
        #pragma unroll
        for (int r = 0; r < 4; ++r)
            mx[r] = fmaxf(fmaxf(Sf[0][r], Sf[1][r]), fmaxf(Sf[2][r], Sf[3][r]));
        #pragma unroll
        for (int off = 1; off < 16; off <<= 1)
            #pragma unroll
            for (int r = 0; r < 4; ++r) mx[r] = fmaxf(mx[r], __shfl_xor(mx[r], off));
        float al[4], rs[4] = {0.f, 0.f, 0.f, 0.f};
        #pragma unroll
        for (int r = 0; r < 4; ++r) {
            float mn = fmaxf(m_[r], mx[r]);
            al[r] = __expf(m_[r] - mn);
            m_[r] = mn;
        }
        float p[4][4];
        #pragma unroll
        for (int n = 0; n < 4; ++n)
            #pragma unroll
            for (int r = 0; r < 4; ++r) {
                p[n][r] = __expf(Sf[n][r] - m_[r]);
                rs[r] += p[n][r];
            }
        #pragma unroll
        for (int off = 1; off < 16; off <<= 1)
            #pragma unroll
            for (int r = 0; r < 4; ++r) rs[r] += __shfl_xor(rs[r], off);
        #pragma unroll
        for (int r = 0; r < 4; ++r) l_[r] = l_[r] * al[r] + rs[r];
        #pragma unroll
        for (int n = 0; n < 4; ++n)
            #pragma unroll
            for (int r = 0; r < 4; ++r) O[n][r] *= al[r];

        // ---- P -> LDS (C-layout -> A-layout; within-wave only) ----
        #pragma unroll
        for (int n = 0; n < 4; ++n)
            #pragma unroll
            for (int r = 0; r < 4; ++r)
                Ps[w * 16 + quad * 4 + r][n * 16 + li] = (__bf16)p[n][r];

        // ---- O += P V ----
        #pragma unroll
        for (int kc = 0; kc < 2; ++kc) {
            bf16x8 Ap = *(const bf16x8*)&Ps[w * 16 + li][kc * 32 + quad * 8];
            #pragma unroll
            for (int n = 0; n < 4; ++n) {
                bf16x8 Bv = *(const bf16x8*)&Vt[n * 16 + li][kc * 32 + quad * 8];
                O[n] = __builtin_amdgcn_mfma_f32_16x16x32_bf16(Ap, Bv, O[n], 0, 0, 0);
            }
        }
    }

    float inv[4];
    #pragma unroll
    for (int r = 0; r < 4; ++r) inv[r] = 1.0f / l_[r];
    #pragma unroll
    for (int n = 0; n < 4; ++n)
        #pragma unroll
        for (int r = 0; r < 4; ++r)
            ao[((size_t)b * Sn + q0 + w * 16 + quad * 4 + r) * Dn + hh * HDn + n * 16 + li]
                = (__bf16)(O[n][r] * inv[r]);
}

// ---------------- Kernel 7: MFMA GEMM  out = ao @ Wo^T + bo ------------------
__global__ __launch_bounds__(256) void k_proj(
        const __bf16* __restrict__ ao, const float* __restrict__ Wo,
        const float* __restrict__ bo, float* __restrict__ out) {
    __shared__ __align__(16) __bf16 As[64][72];
    __shared__ __align__(16) __bf16 Bs[64][72];   // Bs[n][k] = Wo[n0+n][k0+k]
    int bm = blockIdx.x >> 3;
    int bn = blockIdx.x & 7;
    int m0 = bm * 64, n0 = bn * 64;
    int t = threadIdx.x;
    int w = t >> 6, lane = t & 63, quad = lane >> 4, li = lane & 15;

    f32x4 O[4];
    #pragma unroll
    for (int n = 0; n < 4; ++n) O[n] = (f32x4){0.f, 0.f, 0.f, 0.f};

    for (int k0 = 0; k0 < Dn; k0 += 64) {
        if (k0) __syncthreads();
        #pragma unroll
        for (int it = 0; it < 2; ++it) {
            int e = (it * 256 + t) * 8; int r = e >> 6, c = e & 63;
            *(bf16x8*)&As[r][c] = *(const bf16x8*)&ao[(size_t)(m0 + r) * Dn + k0 + c];
        }
        #pragma unroll
        for (int it = 0; it < 4; ++it) {
            int e = (it * 256 + t) * 4; int r = e >> 6, c = e & 63;
            float4 wv = *(const float4*)&Wo[(size_t)(n0 + r) * Dn + k0 + c];
            *(bf16x4*)&Bs[r][c] = (bf16x4){(__bf16)wv.x, (__bf16)wv.y, (__bf16)wv.z, (__bf16)wv.w};
        }
        __syncthreads();

        bf16x8 A0 = *(const bf16x8*)&As[w * 16 + li][quad * 8];
        bf16x8 A1 = *(const bf16x8*)&As[w * 16 + li][32 + quad * 8];
        #pragma unroll
        for (int n = 0; n < 4; ++n) {
            bf16x8 B0 = *(const bf16x8*)&Bs[n * 16 + li][quad * 8];
            O[n] = __builtin_amdgcn_mfma_f32_16x16x32_bf16(A0, B0, O[n], 0, 0, 0);
            bf16x8 B1 = *(const bf16x8*)&Bs[n * 16 + li][32 + quad * 8];
            O[n] = __builtin_amdgcn_mfma_f32_16x16x32_bf16(A1, B1, O[n], 0, 0, 0);
        }
    }

    #pragma unroll
    for (int n = 0; n < 4; ++n) {
        float bias = bo[n0 + n * 16 + li];
        #pragma unroll
        for (int r = 0; r < 4; ++r)
            out[(size_t)(m0 + w * 16 + quad * 4 + r) * Dn + n0 + n * 16 + li] = O[n][r] + bias;
    }
}

extern "C" void kernel_launch(void* const* d_in, const int* in_sizes, int n_in,
                              void* d_out, int out_size, void* d_ws, size_t ws_size,
                              hipStream_t stream) {
    const int*   x   = (const int*)d_in[0];
    const float* emb = (const float*)d_in[1];
    const float* Wq  = (const float*)d_in[2];
    const float* Wk  = (const float*)d_in[3];
    const float* Wv  = (const float*)d_in[4];
    const float* Wo  = (const float*)d_in[5];
    const float* bo  = (const float*)d_in[6];
    const float* Wc  = (const float*)d_in[7];
    const float* bc  = (const float*)d_in[8];

    float* ws    = (float*)d_ws;
    float* h     = ws;                       // reused as ao (bf16) after k_qkv
    float* width = h + (size_t)Bn * Sn * Dn;
    float* lo    = width + Bn * Sn;
    float* hi    = lo + Bn;
    float* wn    = hi + Bn;                  // [B*S] normalized width
    __bf16* qb   = (__bf16*)(wn + Bn * Sn);  // [B,H,S,HD]
    __bf16* kb   = qb + (size_t)Bn * Sn * Dn;
    __bf16* vtb  = kb + (size_t)Bn * Sn * Dn; // [B,H,HD,S]
    __bf16* ao   = (__bf16*)h;               // h dead after k_qkv; bf16 [B,S,D]

    float* out      = (float*)d_out;                      // [B,S,D]
    float* mask_out = out + (size_t)Bn * Sn * Dn;         // [B,S,S]

    k_embed<<<4096, 256, 0, stream>>>(x, emb, h);
    k_width<<<(Bn * Sn) / 4, 256, 0, stream>>>(h, Wc, bc, width);
    k_minmax<<<Bn, 256, 0, stream>>>(width, lo, hi);
    k_mask<<<Bn * Sn, 256, 0, stream>>>(width, lo, hi, mask_out, wn);
    k_qkv<<<(Bn * Sn * Hn) / 64, 256, 0, stream>>>(h, Wq, Wk, Wv, qb, kb, vtb);
    k_attn<<<Bn * Hn * (Sn / 64), 256, 0, stream>>>(qb, kb, vtb, wn, ao);
    k_proj<<<(Bn * Sn / 64) * (Dn / 64), 256, 0, stream>>>(ao, Wo, bo, out);
}

// Round 8
// 223.670 us; speedup vs baseline: 1.2043x; 1.2043x over previous
//
#include <hip/hip_runtime.h>
#include <hip/hip_bf16.h>
#include <math.h>

#define Bn 8
#define Sn 1024
#define Dn 512
#define Hn 8
#define HDn 64

typedef __bf16 bf16x8 __attribute__((ext_vector_type(8)));
typedef __bf16 bf16x4 __attribute__((ext_vector_type(4)));
typedef float  f32x4  __attribute__((ext_vector_type(4)));

// ---------------- Kernel 1: h = emb[x] + positional embedding ----------------
__global__ void k_embed(const int* __restrict__ x, const float* __restrict__ emb,
                        float* __restrict__ h) {
    const int total = Bn * Sn * Dn;
    for (int i = blockIdx.x * blockDim.x + threadIdx.x; i < total; i += gridDim.x * blockDim.x) {
        int d = i & (Dn - 1);
        int bs = i >> 9;           // b*S + s
        int s = bs & (Sn - 1);
        int tok = x[bs];
        float f = __expf((float)(d & ~1) * (-9.210340371976184f / 512.0f));
        float ang = (float)s * f;
        float pe = (d & 1) ? __cosf(ang) : __sinf(ang);
        h[i] = emb[(size_t)tok * Dn + d] + pe;
    }
}

// ---------------- Kernel 2: width[b,s] = h . Wc + bc (one wave per row) ------
__global__ void k_width(const float* __restrict__ h, const float* __restrict__ Wc,
                        const float* __restrict__ bc, float* __restrict__ width) {
    int row = blockIdx.x * 4 + (threadIdx.x >> 6);
    int lane = threadIdx.x & 63;
    const float* hr = h + (size_t)row * Dn;
    float acc = 0.f;
    for (int i = lane; i < Dn; i += 64) acc += hr[i] * Wc[i];
    for (int off = 32; off > 0; off >>= 1) acc += __shfl_down(acc, off);
    if (lane == 0) width[row] = acc + bc[0];
}

// ---------------- Kernel 3: per-batch min/max over S -------------------------
__global__ void k_minmax(const float* __restrict__ width, float* __restrict__ lo,
                         float* __restrict__ hi) {
    int b = blockIdx.x;
    __shared__ float smin[256], smax[256];
    float mn = 1e30f, mx = -1e30f;
    for (int s = threadIdx.x; s < Sn; s += 256) {
        float v = width[b * Sn + s];
        mn = fminf(mn, v);
        mx = fmaxf(mx, v);
    }
    smin[threadIdx.x] = mn; smax[threadIdx.x] = mx;
    __syncthreads();
    for (int off = 128; off; off >>= 1) {
        if (threadIdx.x < off) {
            smin[threadIdx.x] = fminf(smin[threadIdx.x], smin[threadIdx.x + off]);
            smax[threadIdx.x] = fmaxf(smax[threadIdx.x], smax[threadIdx.x + off]);
        }
        __syncthreads();
    }
    if (threadIdx.x == 0) { lo[b] = smin[0]; hi[b] = smax[0]; }
}

// ---------------- Kernel 4: mask -> f32 d_out tail + bf16(mask*SCALE) ws -----
__global__ void k_mask(const float* __restrict__ width, const float* __restrict__ lo,
                       const float* __restrict__ hi, float* __restrict__ mask_out,
                       __bf16* __restrict__ maskb) {
    const float SCALE = 0.04419417382415922f;  // 1/sqrt(512)
    int bs = blockIdx.x;           // b*S + s
    int b = bs >> 10;
    int s = bs & (Sn - 1);
    float wn = (width[bs] - lo[b]) / (hi[b] - lo[b]);
    for (int t = threadIdx.x; t < Sn; t += 256) {
        int it = (t - s + 1535) & (Sn - 1);
        float origin = (it < 512) ? (1.0f - (float)it * (1.0f / 511.0f))
                                  : ((float)(it - 512) * (1.0f / 511.0f));
        float z = (origin - wn) * 100.0f;
        float om;
        if (z >= 0.0f) { float e = __expf(-z); om = e / (1.0f + e); }
        else           { float e = __expf(z);  om = 1.0f / (1.0f + e); }
        bool cmpv = (it >= t);
        bool mv = (s < 512) ? cmpv : !cmpv;
        float val = mv ? om : 0.0f;
        mask_out[(size_t)bs * Sn + t] = val;
        maskb[(size_t)bs * Sn + t] = (__bf16)(val * SCALE);
    }
}

// ---------------- Kernel 5: MFMA q,k,v -------------------------------------
__global__ __launch_bounds__(256) void k_qkv(
        const float* __restrict__ h, const float* __restrict__ Wq,
        const float* __restrict__ Wk, const float* __restrict__ Wv,
        __bf16* __restrict__ q, __bf16* __restrict__ k, __bf16* __restrict__ vt) {
    __shared__ __align__(16) __bf16 Xs[64][72];
    __shared__ __align__(16) __bf16 WqS[64][72];   // [o][d], rows as-is
    __shared__ __align__(16) __bf16 WkS[64][72];
    __shared__ __align__(16) __bf16 WvS[64][72];
    int t = threadIdx.x;
    int m0 = blockIdx.x * 64;          // global row base (R = bs*8 + head)
    int w = t >> 6, lane = t & 63, quad = lane >> 4, li = lane & 15;

    #pragma unroll
    for (int it = 0; it < 4; ++it) {
        int e = (it * 256 + t) * 4; int r = e >> 6, c = e & 63;
        float4 xv = *(const float4*)&h[(size_t)(m0 + r) * 64 + c];
        *(bf16x4*)&Xs[r][c]  = (bf16x4){(__bf16)xv.x, (__bf16)xv.y, (__bf16)xv.z, (__bf16)xv.w};
        float4 qv = *(const float4*)&Wq[e];
        *(bf16x4*)&WqS[r][c] = (bf16x4){(__bf16)qv.x, (__bf16)qv.y, (__bf16)qv.z, (__bf16)qv.w};
        float4 kv = *(const float4*)&Wk[e];
        *(bf16x4*)&WkS[r][c] = (bf16x4){(__bf16)kv.x, (__bf16)kv.y, (__bf16)kv.z, (__bf16)kv.w};
        float4 vv = *(const float4*)&Wv[e];
        *(bf16x4*)&WvS[r][c] = (bf16x4){(__bf16)vv.x, (__bf16)vv.y, (__bf16)vv.z, (__bf16)vv.w};
    }
    __syncthreads();

    bf16x8 A0 = *(const bf16x8*)&Xs[w * 16 + li][quad * 8];
    bf16x8 A1 = *(const bf16x8*)&Xs[w * 16 + li][32 + quad * 8];
    f32x4 aq[4], ak[4], av[4];
    #pragma unroll
    for (int n = 0; n < 4; ++n) {
        aq[n] = (f32x4){0.f,0.f,0.f,0.f}; ak[n] = aq[n]; av[n] = aq[n];
        bf16x8 Bq0 = *(const bf16x8*)&WqS[n * 16 + li][quad * 8];
        bf16x8 Bq1 = *(const bf16x8*)&WqS[n * 16 + li][32 + quad * 8];
        aq[n] = __builtin_amdgcn_mfma_f32_16x16x32_bf16(A0, Bq0, aq[n], 0, 0, 0);
        aq[n] = __builtin_amdgcn_mfma_f32_16x16x32_bf16(A1, Bq1, aq[n], 0, 0, 0);
        bf16x8 Bk0 = *(const bf16x8*)&WkS[n * 16 + li][quad * 8];
        bf16x8 Bk1 = *(const bf16x8*)&WkS[n * 16 + li][32 + quad * 8];
        ak[n] = __builtin_amdgcn_mfma_f32_16x16x32_bf16(A0, Bk0, ak[n], 0, 0, 0);
        ak[n] = __builtin_amdgcn_mfma_f32_16x16x32_bf16(A1, Bk1, ak[n], 0, 0, 0);
        bf16x8 Bv0 = *(const bf16x8*)&WvS[n * 16 + li][quad * 8];
        bf16x8 Bv1 = *(const bf16x8*)&WvS[n * 16 + li][32 + quad * 8];
        av[n] = __builtin_amdgcn_mfma_f32_16x16x32_bf16(A0, Bv0, av[n], 0, 0, 0);
        av[n] = __builtin_amdgcn_mfma_f32_16x16x32_bf16(A1, Bv1, av[n], 0, 0, 0);
    }

    #pragma unroll
    for (int n = 0; n < 4; ++n)
        #pragma unroll
        for (int r = 0; r < 4; ++r) {
            int Rg = m0 + w * 16 + quad * 4 + r;
            int bsI = Rg >> 3, head = Rg & 7;
            int b = bsI >> 10, s = bsI & (Sn - 1);
            size_t oidx = (((size_t)(b * Hn + head)) * Sn + s) * HDn + n * 16 + li;
            q[oidx] = (__bf16)aq[n][r];
            k[oidx] = (__bf16)ak[n][r];
        }

    __bf16 (*Vs)[72] = WqS;
    __syncthreads();
    #pragma unroll
    for (int n = 0; n < 4; ++n)
        #pragma unroll
        for (int r = 0; r < 4; ++r)
            Vs[w * 16 + quad * 4 + r][n * 16 + li] = (__bf16)av[n][r];
    __syncthreads();
    int bs0 = m0 >> 3;
    int b = bs0 >> 10, s0l = bs0 & (Sn - 1);
    #pragma unroll
    for (int i = 0; i < 2; ++i) {
        int p = t + 256 * i;       // (head, o) pair
        int head = p >> 6, o = p & 63;
        __bf16 tmp[8];
        #pragma unroll
        for (int j = 0; j < 8; ++j) tmp[j] = Vs[j * 8 + head][o];
        *(bf16x8*)&vt[(((size_t)(b * Hn + head)) * HDn + o) * Sn + s0l] = *(bf16x8*)tmp;
    }
}

// ---------------- Kernel 6: MFMA flash attention, no-max softmax -------------
// grid decode: hh = blk & 7 (XCD swizzle: same-hh blocks share one XCD's L2
// for the mask slice), qt = (blk>>3)&15, b = blk>>7.
// Energies bounded (|S| <= ~5), so exp(S) is f32-safe: softmax computed
// without max subtraction (shift-invariant => identical math to reference).
// Row sums accumulated per-lane across tiles; single shuffle reduce at end.
__global__ __launch_bounds__(256) void k_attn(
        const __bf16* __restrict__ q, const __bf16* __restrict__ k,
        const __bf16* __restrict__ vt, const __bf16* __restrict__ maskb,
        __bf16* __restrict__ ao) {
    __shared__ __align__(16) __bf16 Ks[64][72];
    __shared__ __align__(16) __bf16 Vt[64][72];   // [o][k_local]
    __shared__ __align__(16) __bf16 Ps[64][76];   // pad 76: quad rows conflict-free
    __shared__ __align__(16) __bf16 Ms[64][76];
    int blk = blockIdx.x;
    int hh = blk & 7;
    int qt = (blk >> 3) & 15;
    int b  = blk >> 7;
    int bh = b * Hn + hh;
    int q0 = qt * 64;
    int t = threadIdx.x;
    int w = t >> 6, lane = t & 63, quad = lane >> 4, li = lane & 15;

    const __bf16* qbase  = q  + ((size_t)bh * Sn + q0) * HDn;
    const __bf16* kbase  = k  + (size_t)bh * Sn * HDn;
    const __bf16* vtbase = vt + (size_t)bh * HDn * Sn;
    const __bf16* mbase  = maskb + ((size_t)hh * Sn + q0) * Sn;  // B==H quirk

    // direct global A-fragments (pattern coalesces: 64B runs over a 2KB span)
    bf16x8 A0 = *(const bf16x8*)&qbase[(w * 16 + li) * HDn + quad * 8];
    bf16x8 A1 = *(const bf16x8*)&qbase[(w * 16 + li) * HDn + 32 + quad * 8];

    f32x4 O[4];
    #pragma unroll
    for (int n = 0; n < 4; ++n) O[n] = (f32x4){0.f, 0.f, 0.f, 0.f};
    float rs[4] = {0.f, 0.f, 0.f, 0.f};

    for (int k0 = 0; k0 < Sn; k0 += 64) {
        if (k0) __syncthreads();
        #pragma unroll
        for (int it = 0; it < 2; ++it) {
            int e = (it * 256 + t) * 8; int r = e >> 6, c = e & 63;
            *(bf16x8*)&Ks[r][c] = *(const bf16x8*)&kbase[(size_t)k0 * HDn + e];
            *(bf16x8*)&Vt[r][c] = *(const bf16x8*)&vtbase[(size_t)r * Sn + k0 + c];
            *(bf16x8*)&Ms[r][c] = *(const bf16x8*)&mbase[(size_t)r * Sn + k0 + c];
        }
        __syncthreads();

        // ---- S = Q K^T, then *= bf16(mask*SCALE) ----
        f32x4 Sf[4];
        #pragma unroll
        for (int n = 0; n < 4; ++n) {
            f32x4 acc = (f32x4){0.f, 0.f, 0.f, 0.f};
            bf16x8 B0 = *(const bf16x8*)&Ks[n * 16 + li][quad * 8];
            acc = __builtin_amdgcn_mfma_f32_16x16x32_bf16(A0, B0, acc, 0, 0, 0);
            bf16x8 B1 = *(const bf16x8*)&Ks[n * 16 + li][32 + quad * 8];
            acc = __builtin_amdgcn_mfma_f32_16x16x32_bf16(A1, B1, acc, 0, 0, 0);
            Sf[n] = acc;
        }

        // ---- p = exp(S*mask), accumulate row sums, stage P ----
        #pragma unroll
        for (int n = 0; n < 4; ++n)
            #pragma unroll
            for (int r = 0; r < 4; ++r) {
                float sv = Sf[n][r] * (float)Ms[w * 16 + quad * 4 + r][n * 16 + li];
                float p = __expf(sv);
                rs[r] += p;
                Ps[w * 16 + quad * 4 + r][n * 16 + li] = (__bf16)p;
            }

        // ---- O += P V ----
        #pragma unroll
        for (int kc = 0; kc < 2; ++kc) {
            bf16x8 Ap = *(const bf16x8*)&Ps[w * 16 + li][kc * 32 + quad * 8];
            #pragma unroll
            for (int n = 0; n < 4; ++n) {
                bf16x8 Bv = *(const bf16x8*)&Vt[n * 16 + li][kc * 32 + quad * 8];
                O[n] = __builtin_amdgcn_mfma_f32_16x16x32_bf16(Ap, Bv, O[n], 0, 0, 0);
            }
        }
    }

    // one reduction at the end (rows live across the 16 lanes of each quad)
    #pragma unroll
    for (int off = 1; off < 16; off <<= 1)
        #pragma unroll
        for (int r = 0; r < 4; ++r) rs[r] += __shfl_xor(rs[r], off);
    float inv[4];
    #pragma unroll
    for (int r = 0; r < 4; ++r) inv[r] = __fdividef(1.0f, rs[r]);
    #pragma unroll
    for (int n = 0; n < 4; ++n)
        #pragma unroll
        for (int r = 0; r < 4; ++r)
            ao[((size_t)b * Sn + q0 + w * 16 + quad * 4 + r) * Dn + hh * HDn + n * 16 + li]
                = (__bf16)(O[n][r] * inv[r]);
}

// ---------------- Kernel 7: MFMA GEMM  out = ao @ Wo^T + bo ------------------
__global__ __launch_bounds__(256) void k_proj(
        const __bf16* __restrict__ ao, const float* __restrict__ Wo,
        const float* __restrict__ bo, float* __restrict__ out) {
    __shared__ __align__(16) __bf16 As[64][72];
    __shared__ __align__(16) __bf16 Bs[64][72];   // Bs[n][k] = Wo[n0+n][k0+k]
    int bm = blockIdx.x >> 3;
    int bn = blockIdx.x & 7;
    int m0 = bm * 64, n0 = bn * 64;
    int t = threadIdx.x;
    int w = t >> 6, lane = t & 63, quad = lane >> 4, li = lane & 15;

    f32x4 O[4];
    #pragma unroll
    for (int n = 0; n < 4; ++n) O[n] = (f32x4){0.f, 0.f, 0.f, 0.f};

    for (int k0 = 0; k0 < Dn; k0 += 64) {
        if (k0) __syncthreads();
        #pragma unroll
        for (int it = 0; it < 2; ++it) {
            int e = (it * 256 + t) * 8; int r = e >> 6, c = e & 63;
            *(bf16x8*)&As[r][c] = *(const bf16x8*)&ao[(size_t)(m0 + r) * Dn + k0 + c];
        }
        #pragma unroll
        for (int it = 0; it < 4; ++it) {
            int e = (it * 256 + t) * 4; int r = e >> 6, c = e & 63;
            float4 wv = *(const float4*)&Wo[(size_t)(n0 + r) * Dn + k0 + c];
            *(bf16x4*)&Bs[r][c] = (bf16x4){(__bf16)wv.x, (__bf16)wv.y, (__bf16)wv.z, (__bf16)wv.w};
        }
        __syncthreads();

        bf16x8 A0 = *(const bf16x8*)&As[w * 16 + li][quad * 8];
        bf16x8 A1 = *(const bf16x8*)&As[w * 16 + li][32 + quad * 8];
        #pragma unroll
        for (int n = 0; n < 4; ++n) {
            bf16x8 B0 = *(const bf16x8*)&Bs[n * 16 + li][quad * 8];
            O[n] = __builtin_amdgcn_mfma_f32_16x16x32_bf16(A0, B0, O[n], 0, 0, 0);
            bf16x8 B1 = *(const bf16x8*)&Bs[n * 16 + li][32 + quad * 8];
            O[n] = __builtin_amdgcn_mfma_f32_16x16x32_bf16(A1, B1, O[n], 0, 0, 0);
        }
    }

    #pragma unroll
    for (int n = 0; n < 4; ++n) {
        float bias = bo[n0 + n * 16 + li];
        #pragma unroll
        for (int r = 0; r < 4; ++r)
            out[(size_t)(m0 + w * 16 + quad * 4 + r) * Dn + n0 + n * 16 + li] = O[n][r] + bias;
    }
}

extern "C" void kernel_launch(void* const* d_in, const int* in_sizes, int n_in,
                              void* d_out, int out_size, void* d_ws, size_t ws_size,
                              hipStream_t stream) {
    const int*   x   = (const int*)d_in[0];
    const float* emb = (const float*)d_in[1];
    const float* Wq  = (const float*)d_in[2];
    const float* Wk  = (const float*)d_in[3];
    const float* Wv  = (const float*)d_in[4];
    const float* Wo  = (const float*)d_in[5];
    const float* bo  = (const float*)d_in[6];
    const float* Wc  = (const float*)d_in[7];
    const float* bc  = (const float*)d_in[8];

    float* ws    = (float*)d_ws;
    float* h     = ws;                       // reused as ao (bf16) after k_qkv
    float* width = h + (size_t)Bn * Sn * Dn;
    float* lo    = width + Bn * Sn;
    float* hi    = lo + Bn;
    __bf16* qb   = (__bf16*)(hi + Bn);       // [B,H,S,HD]
    __bf16* kb   = qb + (size_t)Bn * Sn * Dn;
    __bf16* vtb  = kb + (size_t)Bn * Sn * Dn;   // [B,H,HD,S]
    __bf16* maskb = vtb + (size_t)Bn * Sn * Dn; // [B,S,S] bf16(mask*SCALE)
    __bf16* ao   = (__bf16*)h;               // h dead after k_qkv; bf16 [B,S,D]

    float* out      = (float*)d_out;                      // [B,S,D]
    float* mask_out = out + (size_t)Bn * Sn * Dn;         // [B,S,S]

    k_embed<<<4096, 256, 0, stream>>>(x, emb, h);
    k_width<<<(Bn * Sn) / 4, 256, 0, stream>>>(h, Wc, bc, width);
    k_minmax<<<Bn, 256, 0, stream>>>(width, lo, hi);
    k_mask<<<Bn * Sn, 256, 0, stream>>>(width, lo, hi, mask_out, maskb);
    k_qkv<<<(Bn * Sn * Hn) / 64, 256, 0, stream>>>(h, Wq, Wk, Wv, qb, kb, vtb);
    k_attn<<<Bn * Hn * (Sn / 64), 256, 0, stream>>>(qb, kb, vtb, maskb, ao);
    k_proj<<<(Bn * Sn / 64) * (Dn / 64), 256, 0, stream>>>(ao, Wo, bo, out);
}

// Round 9
// 207.747 us; speedup vs baseline: 1.2966x; 1.0766x over previous
//
#include <hip/hip_runtime.h>
#include <hip/hip_bf16.h>
#include <math.h>

#define Bn 8
#define Sn 1024
#define Dn 512
#define Hn 8
#define HDn 64

typedef __bf16 bf16x8 __attribute__((ext_vector_type(8)));
typedef __bf16 bf16x4 __attribute__((ext_vector_type(4)));
typedef float  f32x4  __attribute__((ext_vector_type(4)));

// monotone float<->uint key for atomic min/max (init = 0xFFFFFFFF for both:
// lo stores min(key), hi stores min(~key))
__device__ __forceinline__ unsigned enc_f(float v) {
    unsigned u = __float_as_uint(v);
    return (u & 0x80000000u) ? ~u : (u | 0x80000000u);
}
__device__ __forceinline__ float dec_f(unsigned k) {
    unsigned u = (k & 0x80000000u) ? (k ^ 0x80000000u) : ~k;
    return __uint_as_float(u);
}

// ------- Kernel 1 (fused): embed+PE -> width (+minmax atomics) -> MFMA qkv ---
// One block = 8 tokens. h never hits global memory.
// Xs rows R = token*8 + (d>>6), cols d&63  (same [64x64] view as before).
__global__ __launch_bounds__(256) void k_fused(
        const int* __restrict__ x, const float* __restrict__ emb,
        const float* __restrict__ Wc, const float* __restrict__ bc,
        const float* __restrict__ Wq, const float* __restrict__ Wk,
        const float* __restrict__ Wv,
        float* __restrict__ width, unsigned* __restrict__ lohi,
        __bf16* __restrict__ q, __bf16* __restrict__ k, __bf16* __restrict__ vt) {
    __shared__ __align__(16) __bf16 Xs[64][72];
    __shared__ __align__(16) __bf16 WqS[64][72];
    __shared__ __align__(16) __bf16 WkS[64][72];
    __shared__ __align__(16) __bf16 WvS[64][72];
    __shared__ float wtok[8];
    int t = threadIdx.x;
    int bs0 = blockIdx.x * 8;
    int m0 = blockIdx.x * 64;
    int w = t >> 6, lane = t & 63, quad = lane >> 4, li = lane & 15;

    // ---- embed + PE + width partial (16 f32 elems per thread, one token) ----
    {
        int token = t >> 5, l32 = t & 31;
        int bs = bs0 + token;
        int s = bs & (Sn - 1);
        int tok = x[bs];
        float wpart = 0.f;
        int row = token * 8 + ((l32 * 16) >> 6);
        #pragma unroll
        for (int j = 0; j < 4; ++j) {
            int d0 = l32 * 16 + j * 4;
            float4 ev = *(const float4*)&emb[(size_t)tok * Dn + d0];
            float4 wc = *(const float4*)&Wc[d0];
            float hv[4];
            #pragma unroll
            for (int i = 0; i < 4; ++i) {
                int d = d0 + i;
                float f = __expf((float)(d & ~1) * (-9.210340371976184f / 512.0f));
                float ang = (float)s * f;
                float pe = (d & 1) ? __cosf(ang) : __sinf(ang);
                hv[i] = (&ev.x)[i] + pe;
                wpart += hv[i] * (&wc.x)[i];
            }
            *(bf16x4*)&Xs[row][d0 & 63] =
                (bf16x4){(__bf16)hv[0], (__bf16)hv[1], (__bf16)hv[2], (__bf16)hv[3]};
        }
        #pragma unroll
        for (int off = 1; off < 32; off <<= 1) wpart += __shfl_xor(wpart, off);
        if (l32 == 0) { float wv = wpart + bc[0]; width[bs] = wv; wtok[token] = wv; }
    }
    // ---- stage weights f32 -> bf16 ----
    #pragma unroll
    for (int it = 0; it < 4; ++it) {
        int e = (it * 256 + t) * 4; int r = e >> 6, c = e & 63;
        float4 qv = *(const float4*)&Wq[e];
        *(bf16x4*)&WqS[r][c] = (bf16x4){(__bf16)qv.x, (__bf16)qv.y, (__bf16)qv.z, (__bf16)qv.w};
        float4 kv = *(const float4*)&Wk[e];
        *(bf16x4*)&WkS[r][c] = (bf16x4){(__bf16)kv.x, (__bf16)kv.y, (__bf16)kv.z, (__bf16)kv.w};
        float4 vv = *(const float4*)&Wv[e];
        *(bf16x4*)&WvS[r][c] = (bf16x4){(__bf16)vv.x, (__bf16)vv.y, (__bf16)vv.z, (__bf16)vv.w};
    }
    __syncthreads();

    if (t == 0) {   // per-block minmax -> 2 encoded atomics
        float mn = wtok[0], mx = wtok[0];
        #pragma unroll
        for (int i = 1; i < 8; ++i) { mn = fminf(mn, wtok[i]); mx = fmaxf(mx, wtok[i]); }
        int b = bs0 >> 10;
        atomicMin(&lohi[b], enc_f(mn));
        atomicMin(&lohi[8 + b], ~enc_f(mx));
    }

    // ---- MFMA qkv ----
    bf16x8 A0 = *(const bf16x8*)&Xs[w * 16 + li][quad * 8];
    bf16x8 A1 = *(const bf16x8*)&Xs[w * 16 + li][32 + quad * 8];
    f32x4 aq[4], ak[4], av[4];
    #pragma unroll
    for (int n = 0; n < 4; ++n) {
        aq[n] = (f32x4){0.f,0.f,0.f,0.f}; ak[n] = aq[n]; av[n] = aq[n];
        bf16x8 Bq0 = *(const bf16x8*)&WqS[n * 16 + li][quad * 8];
        bf16x8 Bq1 = *(const bf16x8*)&WqS[n * 16 + li][32 + quad * 8];
        aq[n] = __builtin_amdgcn_mfma_f32_16x16x32_bf16(A0, Bq0, aq[n], 0, 0, 0);
        aq[n] = __builtin_amdgcn_mfma_f32_16x16x32_bf16(A1, Bq1, aq[n], 0, 0, 0);
        bf16x8 Bk0 = *(const bf16x8*)&WkS[n * 16 + li][quad * 8];
        bf16x8 Bk1 = *(const bf16x8*)&WkS[n * 16 + li][32 + quad * 8];
        ak[n] = __builtin_amdgcn_mfma_f32_16x16x32_bf16(A0, Bk0, ak[n], 0, 0, 0);
        ak[n] = __builtin_amdgcn_mfma_f32_16x16x32_bf16(A1, Bk1, ak[n], 0, 0, 0);
        bf16x8 Bv0 = *(const bf16x8*)&WvS[n * 16 + li][quad * 8];
        bf16x8 Bv1 = *(const bf16x8*)&WvS[n * 16 + li][32 + quad * 8];
        av[n] = __builtin_amdgcn_mfma_f32_16x16x32_bf16(A0, Bv0, av[n], 0, 0, 0);
        av[n] = __builtin_amdgcn_mfma_f32_16x16x32_bf16(A1, Bv1, av[n], 0, 0, 0);
    }

    #pragma unroll
    for (int n = 0; n < 4; ++n)
        #pragma unroll
        for (int r = 0; r < 4; ++r) {
            int Rg = m0 + w * 16 + quad * 4 + r;
            int bsI = Rg >> 3, head = Rg & 7;
            int b = bsI >> 10, s = bsI & (Sn - 1);
            size_t oidx = (((size_t)(b * Hn + head)) * Sn + s) * HDn + n * 16 + li;
            q[oidx] = (__bf16)aq[n][r];
            k[oidx] = (__bf16)ak[n][r];
        }

    __bf16 (*Vs)[72] = WqS;
    __syncthreads();
    #pragma unroll
    for (int n = 0; n < 4; ++n)
        #pragma unroll
        for (int r = 0; r < 4; ++r)
            Vs[w * 16 + quad * 4 + r][n * 16 + li] = (__bf16)av[n][r];
    __syncthreads();
    int bs0i = m0 >> 3;
    int b = bs0i >> 10, s0l = bs0i & (Sn - 1);
    #pragma unroll
    for (int i = 0; i < 2; ++i) {
        int p = t + 256 * i;       // (head, o) pair
        int head = p >> 6, o = p & 63;
        __bf16 tmp[8];
        #pragma unroll
        for (int j = 0; j < 8; ++j) tmp[j] = Vs[j * 8 + head][o];
        *(bf16x8*)&vt[(((size_t)(b * Hn + head)) * HDn + o) * Sn + s0l] = *(bf16x8*)tmp;
    }
}

// ---------------- Kernel 2: mask -> f32 d_out tail + bf16(mask*SCALE) ws -----
__global__ void k_mask(const float* __restrict__ width, const unsigned* __restrict__ lohi,
                       float* __restrict__ mask_out, __bf16* __restrict__ maskb) {
    const float SCALE = 0.04419417382415922f;  // 1/sqrt(512)
    int bs = blockIdx.x;           // b*S + s
    int b = bs >> 10;
    int s = bs & (Sn - 1);
    float lo = dec_f(lohi[b]);
    float hi = dec_f(~lohi[8 + b]);
    float wn = (width[bs] - lo) / (hi - lo);
    for (int t = threadIdx.x; t < Sn; t += 256) {
        int it = (t - s + 1535) & (Sn - 1);
        float origin = (it < 512) ? (1.0f - (float)it * (1.0f / 511.0f))
                                  : ((float)(it - 512) * (1.0f / 511.0f));
        float z = (origin - wn) * 100.0f;
        float om;
        if (z >= 0.0f) { float e = __expf(-z); om = e / (1.0f + e); }
        else           { float e = __expf(z);  om = 1.0f / (1.0f + e); }
        bool cmpv = (it >= t);
        bool mv = (s < 512) ? cmpv : !cmpv;
        float val = mv ? om : 0.0f;
        mask_out[(size_t)bs * Sn + t] = val;
        maskb[(size_t)bs * Sn + t] = (__bf16)(val * SCALE);
    }
}

// ---------------- Kernel 3: MFMA flash attention -----------------------------
// hh = blk&7 (XCD swizzle), no-max softmax, mask read direct from global in
// C-layout (L2-resident), register prefetch of next K/V tile.
__global__ __launch_bounds__(256) void k_attn(
        const __bf16* __restrict__ q, const __bf16* __restrict__ k,
        const __bf16* __restrict__ vt, const __bf16* __restrict__ maskb,
        __bf16* __restrict__ ao) {
    __shared__ __align__(16) __bf16 Ks[64][72];
    __shared__ __align__(16) __bf16 Vt[64][72];   // [o][k_local]
    __shared__ __align__(16) __bf16 Ps[64][76];
    int blk = blockIdx.x;
    int hh = blk & 7;
    int qt = (blk >> 3) & 15;
    int b  = blk >> 7;
    int bh = b * Hn + hh;
    int q0 = qt * 64;
    int t = threadIdx.x;
    int w = t >> 6, lane = t & 63, quad = lane >> 4, li = lane & 15;

    const __bf16* qbase  = q  + ((size_t)bh * Sn + q0) * HDn;
    const __bf16* kbase  = k  + (size_t)bh * Sn * HDn;
    const __bf16* vtbase = vt + (size_t)bh * HDn * Sn;
    const __bf16* mrow[4];
    #pragma unroll
    for (int r = 0; r < 4; ++r)
        mrow[r] = maskb + ((size_t)hh * Sn + q0 + w * 16 + quad * 4 + r) * Sn;  // B==H quirk

    bf16x8 A0 = *(const bf16x8*)&qbase[(w * 16 + li) * HDn + quad * 8];
    bf16x8 A1 = *(const bf16x8*)&qbase[(w * 16 + li) * HDn + 32 + quad * 8];

    // prefetch tile 0 into registers
    bf16x8 pk[2], pv[2];
    #pragma unroll
    for (int it = 0; it < 2; ++it) {
        int e = (it * 256 + t) * 8; int r = e >> 6, c = e & 63;
        pk[it] = *(const bf16x8*)&kbase[e];
        pv[it] = *(const bf16x8*)&vtbase[(size_t)r * Sn + c];
    }

    f32x4 O[4];
    #pragma unroll
    for (int n = 0; n < 4; ++n) O[n] = (f32x4){0.f, 0.f, 0.f, 0.f};
    float rs[4] = {0.f, 0.f, 0.f, 0.f};

    for (int k0 = 0; k0 < Sn; k0 += 64) {
        if (k0) __syncthreads();
        #pragma unroll
        for (int it = 0; it < 2; ++it) {
            int e = (it * 256 + t) * 8; int r = e >> 6, c = e & 63;
            *(bf16x8*)&Ks[r][c] = pk[it];
            *(bf16x8*)&Vt[r][c] = pv[it];
        }
        __syncthreads();
        if (k0 + 64 < Sn) {
            #pragma unroll
            for (int it = 0; it < 2; ++it) {
                int e = (it * 256 + t) * 8; int r = e >> 6, c = e & 63;
                pk[it] = *(const bf16x8*)&kbase[(size_t)(k0 + 64) * HDn + e];
                pv[it] = *(const bf16x8*)&vtbase[(size_t)r * Sn + (k0 + 64) + c];
            }
        }

        // ---- mask (direct global, C-layout) ----
        float msk[4][4];
        #pragma unroll
        for (int n = 0; n < 4; ++n)
            #pragma unroll
            for (int r = 0; r < 4; ++r)
                msk[n][r] = (float)mrow[r][k0 + n * 16 + li];

        // ---- S = Q K^T ----
        f32x4 Sf[4];
        #pragma unroll
        for (int n = 0; n < 4; ++n) {
            f32x4 acc = (f32x4){0.f, 0.f, 0.f, 0.f};
            bf16x8 B0 = *(const bf16x8*)&Ks[n * 16 + li][quad * 8];
            acc = __builtin_amdgcn_mfma_f32_16x16x32_bf16(A0, B0, acc, 0, 0, 0);
            bf16x8 B1 = *(const bf16x8*)&Ks[n * 16 + li][32 + quad * 8];
            acc = __builtin_amdgcn_mfma_f32_16x16x32_bf16(A1, B1, acc, 0, 0, 0);
            Sf[n] = acc;
        }

        // ---- p = exp(S*mask), row-sum partials, stage P ----
        #pragma unroll
        for (int n = 0; n < 4; ++n)
            #pragma unroll
            for (int r = 0; r < 4; ++r) {
                float p = __expf(Sf[n][r] * msk[n][r]);
                rs[r] += p;
                Ps[w * 16 + quad * 4 + r][n * 16 + li] = (__bf16)p;
            }

        // ---- O += P V ----
        #pragma unroll
        for (int kc = 0; kc < 2; ++kc) {
            bf16x8 Ap = *(const bf16x8*)&Ps[w * 16 + li][kc * 32 + quad * 8];
            #pragma unroll
            for (int n = 0; n < 4; ++n) {
                bf16x8 Bv = *(const bf16x8*)&Vt[n * 16 + li][kc * 32 + quad * 8];
                O[n] = __builtin_amdgcn_mfma_f32_16x16x32_bf16(Ap, Bv, O[n], 0, 0, 0);
            }
        }
    }

    #pragma unroll
    for (int off = 1; off < 16; off <<= 1)
        #pragma unroll
        for (int r = 0; r < 4; ++r) rs[r] += __shfl_xor(rs[r], off);
    float inv[4];
    #pragma unroll
    for (int r = 0; r < 4; ++r) inv[r] = __fdividef(1.0f, rs[r]);
    #pragma unroll
    for (int n = 0; n < 4; ++n)
        #pragma unroll
        for (int r = 0; r < 4; ++r)
            ao[((size_t)b * Sn + q0 + w * 16 + quad * 4 + r) * Dn + hh * HDn + n * 16 + li]
                = (__bf16)(O[n][r] * inv[r]);
}

// ---------------- Kernel 4: MFMA GEMM  out = ao @ Wo^T + bo ------------------
__global__ __launch_bounds__(256) void k_proj(
        const __bf16* __restrict__ ao, const float* __restrict__ Wo,
        const float* __restrict__ bo, float* __restrict__ out) {
    __shared__ __align__(16) __bf16 As[64][72];
    __shared__ __align__(16) __bf16 Bs[64][72];   // Bs[n][k] = Wo[n0+n][k0+k]
    int bm = blockIdx.x >> 3;
    int bn = blockIdx.x & 7;
    int m0 = bm * 64, n0 = bn * 64;
    int t = threadIdx.x;
    int w = t >> 6, lane = t & 63, quad = lane >> 4, li = lane & 15;

    f32x4 O[4];
    #pragma unroll
    for (int n = 0; n < 4; ++n) O[n] = (f32x4){0.f, 0.f, 0.f, 0.f};

    for (int k0 = 0; k0 < Dn; k0 += 64) {
        if (k0) __syncthreads();
        #pragma unroll
        for (int it = 0; it < 2; ++it) {
            int e = (it * 256 + t) * 8; int r = e >> 6, c = e & 63;
            *(bf16x8*)&As[r][c] = *(const bf16x8*)&ao[(size_t)(m0 + r) * Dn + k0 + c];
        }
        #pragma unroll
        for (int it = 0; it < 4; ++it) {
            int e = (it * 256 + t) * 4; int r = e >> 6, c = e & 63;
            float4 wv = *(const float4*)&Wo[(size_t)(n0 + r) * Dn + k0 + c];
            *(bf16x4*)&Bs[r][c] = (bf16x4){(__bf16)wv.x, (__bf16)wv.y, (__bf16)wv.z, (__bf16)wv.w};
        }
        __syncthreads();

        bf16x8 A0 = *(const bf16x8*)&As[w * 16 + li][quad * 8];
        bf16x8 A1 = *(const bf16x8*)&As[w * 16 + li][32 + quad * 8];
        #pragma unroll
        for (int n = 0; n < 4; ++n) {
            bf16x8 B0 = *(const bf16x8*)&Bs[n * 16 + li][quad * 8];
            O[n] = __builtin_amdgcn_mfma_f32_16x16x32_bf16(A0, B0, O[n], 0, 0, 0);
            bf16x8 B1 = *(const bf16x8*)&Bs[n * 16 + li][32 + quad * 8];
            O[n] = __builtin_amdgcn_mfma_f32_16x16x32_bf16(A1, B1, O[n], 0, 0, 0);
        }
    }

    #pragma unroll
    for (int n = 0; n < 4; ++n) {
        float bias = bo[n0 + n * 16 + li];
        #pragma unroll
        for (int r = 0; r < 4; ++r)
            out[(size_t)(m0 + w * 16 + quad * 4 + r) * Dn + n0 + n * 16 + li] = O[n][r] + bias;
    }
}

extern "C" void kernel_launch(void* const* d_in, const int* in_sizes, int n_in,
                              void* d_out, int out_size, void* d_ws, size_t ws_size,
                              hipStream_t stream) {
    const int*   x   = (const int*)d_in[0];
    const float* emb = (const float*)d_in[1];
    const float* Wq  = (const float*)d_in[2];
    const float* Wk  = (const float*)d_in[3];
    const float* Wv  = (const float*)d_in[4];
    const float* Wo  = (const float*)d_in[5];
    const float* bo  = (const float*)d_in[6];
    const float* Wc  = (const float*)d_in[7];
    const float* bc  = (const float*)d_in[8];

    float* ws      = (float*)d_ws;
    float* width   = ws;                          // [B*S]
    unsigned* lohi = (unsigned*)(width + Bn * Sn); // [16] encoded min/max keys
    __bf16* qb   = (__bf16*)(ws + Bn * Sn + 16);  // [B,H,S,HD]
    __bf16* kb   = qb + (size_t)Bn * Sn * Dn;
    __bf16* vtb  = kb + (size_t)Bn * Sn * Dn;     // [B,H,HD,S]
    __bf16* maskb = vtb + (size_t)Bn * Sn * Dn;   // [B,S,S] bf16(mask*SCALE)
    __bf16* ao   = maskb + (size_t)Bn * Sn * Sn;  // [B,S,D] bf16

    float* out      = (float*)d_out;              // [B,S,D]
    float* mask_out = out + (size_t)Bn * Sn * Dn; // [B,S,S]

    hipMemsetAsync(lohi, 0xFF, 16 * sizeof(unsigned), stream);
    k_fused<<<(Bn * Sn) / 8, 256, 0, stream>>>(x, emb, Wc, bc, Wq, Wk, Wv,
                                               width, lohi, qb, kb, vtb);
    k_mask<<<Bn * Sn, 256, 0, stream>>>(width, lohi, mask_out, maskb);
    k_attn<<<Bn * Hn * (Sn / 64), 256, 0, stream>>>(qb, kb, vtb, maskb, ao);
    k_proj<<<(Bn * Sn / 64) * (Dn / 64), 256, 0, stream>>>(ao, Wo, bo, out);
}